// Round 6
// baseline (230.625 us; speedup 1.0000x reference)
//
#include <hip/hip_runtime.h>
#include <math.h>

#define LN_EPS 1e-5f

typedef _Float16 h2v __attribute__((ext_vector_type(2)));

__device__ __forceinline__ float dot4(float4 a, float4 b) {
    return a.x*b.x + a.y*b.y + a.z*b.z + a.w*b.w;
}
__device__ __forceinline__ void fma4(float4& a, float s, float4 v) {
    a.x += s*v.x; a.y += s*v.y; a.z += s*v.z; a.w += s*v.w;
}
__device__ __forceinline__ float fast_rcp(float x) {
    return __builtin_amdgcn_rcpf(x);       // v_rcp_f32: 1 instr vs ~10-op IEEE div
}
__device__ __forceinline__ float fast_sigmoid(float x) {
    return fast_rcp(1.f + __expf(-x));     // +-inf safe
}
__device__ __forceinline__ float fast_tanh(float x) {
    return 1.f - 2.f*fast_rcp(__expf(2.f*x) + 1.f);   // +-inf safe
}
__device__ __forceinline__ float fdot2u(unsigned int a, unsigned int b, float c) {
#if __has_builtin(__builtin_amdgcn_fdot2)
    return __builtin_amdgcn_fdot2(__builtin_bit_cast(h2v, a),
                                  __builtin_bit_cast(h2v, b), c, false);
#else
    const h2v av = __builtin_bit_cast(h2v, a);
    const h2v bv = __builtin_bit_cast(h2v, b);
    return c + (float)av[0]*(float)bv[0] + (float)av[1]*(float)bv[1];
#endif
}
__device__ __forceinline__ float wsum64(float v) {
    #pragma unroll
    for (int off = 32; off > 0; off >>= 1) v += __shfl_xor(v, off);
    return v;
}
// pair (2-lane) butterfly add via DPP quad_perm — VALU-speed, no LDS pipe.
__device__ __forceinline__ float qadd_xor1(float v) {
    const int x = __builtin_amdgcn_mov_dpp(__builtin_bit_cast(int, v),
                                           0xB1 /*perm(1,0,3,2)*/, 0xF, 0xF, true);
    return v + __builtin_bit_cast(float, x);
}

// ---------------------------------------------------------------------------
// Kernel 1: blocks 0..63 = xm transpose; 64..71 = query rows (16/blk);
// 72..327 = key rows (16/blk) -> kT[b][d][t].
// R13: 16 rows/block (was 4) — amortizes the 64KB W read 4x (64->16 MB L2
// traffic) and cuts dispatch rounds 4.4 -> 1.3.
// ---------------------------------------------------------------------------
__global__ void k_embed_proj(
    const float* __restrict__ input, const float* __restrict__ mask,
    const float* __restrict__ timesteps,
    const float* __restrict__ pw, const float* __restrict__ pb,
    const float* __restrict__ lw, const float* __restrict__ lb,
    const float* __restrict__ q_w, const float* __restrict__ q_b,
    const float* __restrict__ q_g, const float* __restrict__ q_be,
    const float* __restrict__ k_w, const float* __restrict__ k_b,
    const float* __restrict__ k_g, const float* __restrict__ k_be,
    float* __restrict__ qs, float* __restrict__ kT, float2* __restrict__ xm)
{
    const int blk = blockIdx.x;
    const int tid = threadIdx.x;          // 0..127

    __shared__ __align__(16) float e[16][128];
    __shared__ __align__(16) float proj[16][128];
    __shared__ __align__(16) float2 tile[32][65];
    __shared__ __align__(16) float red2[2][16];
    __shared__ __align__(16) float red2b[2][16];

    if (blk < 64) {
        // ---- xm transpose: 8 blocks per b, 64 t each ----
        const int b  = blk >> 3;
        const int t0 = (blk & 7) * 64;
        const int cg = tid >> 6;          // 0..1
        const int tt = tid & 63;
        #pragma unroll
        for (int c16 = 0; c16 < 16; ++c16) {
            const int c = c16*2 + cg;
            const float m = mask [(size_t)(b*32 + c)*512 + t0 + tt];
            const float x = input[(size_t)(b*32 + c)*512 + t0 + tt];
            const float mm = 1.0f - m;
            tile[c][tt] = make_float2(x*mm, mm);
        }
        __syncthreads();
        const int c2 = tid & 31;
        const int tg = tid >> 5;          // 0..3
        #pragma unroll
        for (int k = 0; k < 16; ++k) {
            const int t = tg*16 + k;
            xm[((size_t)b*512 + t0 + t)*32 + c2] = tile[c2][t];
        }
        return;
    }

    const bool isq = blk < 72;
    float tv[16];
    int kidx0 = 0, q0 = 0;
    if (isq) {
        q0 = (blk - 64) * 16;
        #pragma unroll
        for (int r = 0; r < 16; ++r) tv[r] = (float)(q0 + r) * (1.0f/127.0f);
    } else {
        kidx0 = (blk - 72) * 16;
        #pragma unroll
        for (int r = 0; r < 16; ++r) tv[r] = timesteps[kidx0 + r];
    }

    float pwj = 0.f, pbj = 0.f;
    if (tid > 0) { pwj = pw[tid-1]; pbj = pb[tid-1]; }
    const float lw0 = lw[0], lb0 = lb[0];
    #pragma unroll
    for (int r = 0; r < 16; ++r)
        e[r][tid] = (tid == 0) ? (tv[r]*lw0 + lb0) : __sinf(tv[r]*pwj + pbj);
    __syncthreads();

    const float* W  = isq ? q_w  : k_w;
    const float* Bv = isq ? q_b  : k_b;
    const float* G  = isq ? q_g  : k_g;
    const float* Be = isq ? q_be : k_be;

    {
        const int jj = tid >> 2, dc = tid & 3;
        #pragma unroll
        for (int jb = 0; jb < 4; ++jb) {
            const int j = jb*32 + jj;
            const float4* wrow = (const float4*)(W + (size_t)j*128);
            float a[16];
            #pragma unroll
            for (int r = 0; r < 16; ++r) a[r] = 0.f;
            #pragma unroll
            for (int k = 0; k < 8; ++k) {
                const int idx = dc + 4*k;
                const float4 w4 = wrow[idx];
                #pragma unroll
                for (int r = 0; r < 16; ++r)
                    a[r] += dot4(w4, ((const float4*)e[r])[idx]);
            }
            #pragma unroll
            for (int r = 0; r < 16; ++r) {
                a[r] += __shfl_xor(a[r], 1, 4);
                a[r] += __shfl_xor(a[r], 2, 4);
            }
            if (dc == 0) {
                const float bj = Bv[j];
                #pragma unroll
                for (int r = 0; r < 16; ++r) proj[r][j] = a[r] + bj;
            }
        }
    }
    __syncthreads();

    float acc[16];
    #pragma unroll
    for (int r = 0; r < 16; ++r) acc[r] = proj[r][tid];

    // ---- LN mean via per-wave shfl reduce + 2-slot combine ----
    #pragma unroll
    for (int r = 0; r < 16; ++r) {
        const float m = wsum64(acc[r]);
        if ((tid & 63) == 0) red2[tid >> 6][r] = m;
    }
    __syncthreads();
    float d[16];
    #pragma unroll
    for (int r = 0; r < 16; ++r)
        d[r] = acc[r] - (red2[0][r] + red2[1][r]) * (1.0f/128.0f);
    #pragma unroll
    for (int r = 0; r < 16; ++r) {
        const float v = wsum64(d[r]*d[r]);
        if ((tid & 63) == 0) red2b[tid >> 6][r] = v;
    }
    __syncthreads();

    const float gg = G[tid], bb = Be[tid];
    float o[16];
    #pragma unroll
    for (int r = 0; r < 16; ++r) {
        const float var = (red2b[0][r] + red2b[1][r]) * (1.0f/128.0f);
        o[r] = d[r]*rsqrtf(var+LN_EPS)*gg + bb;
    }

    if (isq) {
        const float sc = 0.08838834764831845f;   // 1/sqrt(128)
        #pragma unroll
        for (int r = 0; r < 16; ++r)
            qs[(size_t)(q0+r)*128 + tid] = o[r]*sc;
    } else {
        const int b = kidx0 >> 9;
        const int t = kidx0 & 511;
        float* dst = kT + ((size_t)(b*128 + tid))*512 + t;
        *(float4*)(dst)      = make_float4(o[0],  o[1],  o[2],  o[3]);
        *(float4*)(dst + 4)  = make_float4(o[4],  o[5],  o[6],  o[7]);
        *(float4*)(dst + 8)  = make_float4(o[8],  o[9],  o[10], o[11]);
        *(float4*)(dst + 12) = make_float4(o[12], o[13], o[14], o[15]);
    }
}

// ---------------------------------------------------------------------------
// Kernel 2: attention + fused gi. 256 blocks = (b, 4 qi), 256 threads.
// R13: k_gi fused in — the block already holds its 4 outm rows; keep them in
// LDS (om), compute gi = om·wih^T + bih with the 4-lane-cooperative pattern,
// write gi directly. Removes one launch + the outm global round trip.
// ---------------------------------------------------------------------------
__global__ void __launch_bounds__(256) k_attn(
    const float2* __restrict__ xm,
    const float* __restrict__ qs, const float* __restrict__ kT,
    const float* __restrict__ attn_g, const float* __restrict__ attn_b,
    const float* __restrict__ out_w, const float* __restrict__ out_b,
    const float* __restrict__ out_g, const float* __restrict__ out_be,
    const float* __restrict__ wih, const float* __restrict__ bih,
    float* __restrict__ gi)
{
    const int b     = blockIdx.x >> 5;
    const int qbase = (blockIdx.x & 31) * 4;
    const int tid   = threadIdx.x;          // 0..255

    __shared__ __align__(16) float et[4][512];
    __shared__ __align__(16) float qsh[4][128];
    __shared__ __align__(16) float wsh[128*66];
    __shared__ __align__(16) float sA[4][8][32];
    __shared__ __align__(16) float aA[4][8][32];
    __shared__ __align__(16) float x2s[4][64];
    __shared__ __align__(16) float om[4][128];
    __shared__ float redC[4];

    for (int idx = tid; idx < 512; idx += 256)
        qsh[idx >> 7][idx & 127] = qs[(size_t)(qbase + (idx >> 7))*128 + (idx & 127)];
    __syncthreads();

    // ---- scores: group handles 2 qi; 4-deep register pipeline on kT ----
    {
        const int grp = tid >> 7;
        const int tl  = tid & 127;
        const int q0  = grp*2;
        const float4* kp  = (const float4*)kT + (size_t)b*128*128 + tl;
        const float4* qa4 = (const float4*)qsh[q0];
        const float4* qb4 = (const float4*)qsh[q0+1];
        float4 a0 = make_float4(0,0,0,0), a1 = make_float4(0,0,0,0);
        float4 c0 = kp[0], c1 = kp[128], c2 = kp[256], c3 = kp[384];
        for (int c = 0; c < 32; ++c) {
            float4 n0, n1, n2, n3;
            if (c < 31) {
                const float4* kn = kp + (size_t)(4*c+4)*128;
                n0 = kn[0]; n1 = kn[128]; n2 = kn[256]; n3 = kn[384];
            }
            const float4 qa = qa4[c], qb = qb4[c];
            fma4(a0, qa.x, c0); fma4(a1, qb.x, c0);
            fma4(a0, qa.y, c1); fma4(a1, qb.y, c1);
            fma4(a0, qa.z, c2); fma4(a1, qb.z, c2);
            fma4(a0, qa.w, c3); fma4(a1, qb.w, c3);
            c0 = n0; c1 = n1; c2 = n2; c3 = n3;
        }
        a0.x = __expf(a0.x); a0.y = __expf(a0.y); a0.z = __expf(a0.z); a0.w = __expf(a0.w);
        a1.x = __expf(a1.x); a1.y = __expf(a1.y); a1.z = __expf(a1.z); a1.w = __expf(a1.w);
        ((float4*)et[q0])[tl]   = a0;
        ((float4*)et[q0+1])[tl] = a1;
    }
    // stage out_w while et/xm phases run (needed only in the out-proj phase)
    for (int idx = tid; idx < 8192; idx += 256)
        wsh[(idx >> 6)*66 + (idx & 63)] = out_w[idx];
    __syncthreads();

    {
        const int c   = tid & 31;
        const int seg = tid >> 5;
        const float2* xp = xm + ((size_t)b*512 + seg*64)*32 + c;
        float s0=0,s1=0,s2=0,s3=0, a0=0,a1=0,a2=0,a3=0;
        #pragma unroll 4
        for (int i = 0; i < 64; ++i) {
            const float2 v = xp[(size_t)i*32];
            const int t = seg*64 + i;
            const float w0 = et[0][t]*v.y, w1 = et[1][t]*v.y;
            const float w2 = et[2][t]*v.y, w3 = et[3][t]*v.y;
            s0 += w0; s1 += w1; s2 += w2; s3 += w3;
            a0 += w0*v.x; a1 += w1*v.x; a2 += w2*v.x; a3 += w3*v.x;
        }
        sA[0][seg][c]=s0; sA[1][seg][c]=s1; sA[2][seg][c]=s2; sA[3][seg][c]=s3;
        aA[0][seg][c]=a0; aA[1][seg][c]=a1; aA[2][seg][c]=a2; aA[3][seg][c]=a3;
    }
    __syncthreads();

    {
        const int ql = tid >> 6;
        const int c2 = tid & 63;
        const int cc = c2 & 31;
        float ss = 0.f;
        #pragma unroll
        for (int g = 0; g < 8; ++g) ss += sA[ql][g][cc];
        float attv;
        if (c2 < 32) {
            float aa = 0.f;
            #pragma unroll
            for (int g = 0; g < 8; ++g) aa += aA[ql][g][cc];
            attv = (ss > 0.f) ? aa/ss : 0.f;
        } else {
            attv = (ss > 0.f) ? 1.0f : 0.0f;
        }
        const float mean = wsum64(attv) * (1.0f/64.0f);
        const float dv = attv - mean;
        const float var = wsum64(dv*dv) * (1.0f/64.0f);
        x2s[ql][c2] = dv*rsqrtf(var+LN_EPS)*attn_g[c2] + attn_b[c2];
    }
    __syncthreads();

    {
        const int jhalf = tid >> 7;
        const int j     = tid & 127;
        const int wave  = tid >> 6;
        for (int lq2 = 0; lq2 < 2; ++lq2) {
            const int ql = jhalf*2 + lq2;
            float acc = out_b[j];
            const float4* wrow = (const float4*)(wsh + j*66);
            const float4* xr   = (const float4*)x2s[ql];
            #pragma unroll
            for (int k = 0; k < 16; ++k) acc += dot4(wrow[k], xr[k]);

            float v = wsum64(acc);
            if ((tid & 63) == 0) redC[wave] = v;
            __syncthreads();
            const float mean = (redC[jhalf*2] + redC[jhalf*2+1]) * (1.0f/128.0f);
            __syncthreads();
            const float d = acc - mean;
            v = wsum64(d*d);
            if ((tid & 63) == 0) redC[wave] = v;
            __syncthreads();
            const float var = (redC[jhalf*2] + redC[jhalf*2+1]) * (1.0f/128.0f);
            om[ql][j] = d*rsqrtf(var+LN_EPS)*out_g[j] + out_be[j];
            __syncthreads();
        }
    }

    // ---- fused gi: gi[(qi*8+b)*384+g] = om[ql]·wih[g,:] + bih[g] ----
    {
        const int grp = tid >> 2;          // 0..63
        const int dc  = tid & 3;
        #pragma unroll
        for (int gb = 0; gb < 6; ++gb) {
            const int g = gb*64 + grp;     // 0..383
            const float4* wrow = (const float4*)(wih + (size_t)g*128);
            float acc[4] = {0,0,0,0};
            #pragma unroll
            for (int k = 0; k < 8; ++k) {
                const int idx = dc + 4*k;
                const float4 w4 = wrow[idx];
                #pragma unroll
                for (int ql = 0; ql < 4; ++ql)
                    acc[ql] += dot4(w4, ((const float4*)om[ql])[idx]);
            }
            #pragma unroll
            for (int ql = 0; ql < 4; ++ql) {
                acc[ql] += __shfl_xor(acc[ql], 1, 4);
                acc[ql] += __shfl_xor(acc[ql], 2, 4);
            }
            if (dc == 0) {
                const float bi = bih[g];
                #pragma unroll
                for (int ql = 0; ql < 4; ++ql)
                    gi[((size_t)(qbase+ql)*8 + b)*384 + g] = acc[ql] + bi;
            }
        }
    }
}

// ---------------------------------------------------------------------------
// Kernel 3: GRU + fused classifier. 8 blocks x 256 threads (4 waves, 1/SIMD).
// R13 = exact revert to the best-measured R10/R3 configuration (63.0 us).
// The R12 experiments (lgkm-only barrier, forced LDS materialization) were
// both refuted (65.4); the ~500cyc/step non-issue time is latency that
// 1 wave/SIMD cannot hide, and the 256-VGPR/wave cap forbids fewer waves.
// ---------------------------------------------------------------------------
__global__ void __launch_bounds__(256) k_gru_cls(
    const float* __restrict__ gi,
    const float* __restrict__ whh, const float* __restrict__ bhh,
    const float* __restrict__ c1w, const float* __restrict__ c1b,
    const float* __restrict__ c2w, const float* __restrict__ c2b,
    const float* __restrict__ c3w, const float* __restrict__ c3b,
    float* __restrict__ out)
{
    const int b   = blockIdx.x;
    const int tid = threadIdx.x;                 // 0..255
    const int u   = tid >> 1;                    // unit 0..127
    const int s   = tid & 1;                     // 64-col k-slice 0..1

    __shared__ __align__(16) _Float16 hbuf[2][128];      // h as fp16, dbuf
    __shared__ __align__(16) float hcls[128];
    __shared__ __align__(16) float scr[256];

    // ---- whh rows {u, u+128, u+256}, cols [64s,64s+64) -> fp16 pairs in regs
    unsigned int wreg[3][32];
    #pragma unroll
    for (int g = 0; g < 3; ++g) {
        const float4* wrow = (const float4*)(whh + (size_t)(g*128 + u)*128 + 64*s);
        #pragma unroll
        for (int i = 0; i < 16; ++i) {
            const float4 v = wrow[i];
            h2v p0; p0[0] = (_Float16)v.x; p0[1] = (_Float16)v.y;
            h2v p1; p1[0] = (_Float16)v.z; p1[1] = (_Float16)v.w;
            wreg[g][2*i]   = __builtin_bit_cast(unsigned int, p0);
            wreg[g][2*i+1] = __builtin_bit_cast(unsigned int, p1);
        }
    }
    const float bh_r = bhh[u], bh_z = bhh[u+128], bh_n = bhh[u+256];

    const float* gpR = gi + (size_t)b*384 + u;
    const float* gpZ = gpR + 128;
    const float* gpN = gpR + 256;

    // 4-deep gi pipeline: slot j holds step qi+j (compile-time indices only).
    float gR[4], gZ[4], gN[4];
    #pragma unroll
    for (int j = 0; j < 4; ++j) {
        gR[j] = gpR[(size_t)j*3072];
        gZ[j] = gpZ[(size_t)j*3072];
        gN[j] = gpN[(size_t)j*3072];
    }

    if (tid < 128) { hbuf[0][tid] = (_Float16)0.f; hbuf[1][tid] = (_Float16)0.f; }
    float hprev = 0.f;
    __syncthreads();

    // Body J (step qi+J): read h from hbuf[RB], write new h to hbuf[WB].
    // Consumes gi slot J, then reloads it for step PF = qi+4+J (clamped).
#define GRU_BODY(RB, WB, J, PF)                                                \
    {                                                                          \
        const float giR = gR[J], giZ = gZ[J], giN = gN[J];                     \
        gR[J] = gpR[(size_t)(PF)*3072];                                        \
        gZ[J] = gpZ[(size_t)(PF)*3072];                                        \
        gN[J] = gpN[(size_t)(PF)*3072];                                        \
        const uint4* hp4 = (const uint4*)&hbuf[RB][0] + s*8;                   \
        uint4 hv[8];                                                           \
        _Pragma("unroll")                                                      \
        for (int i = 0; i < 8; ++i) hv[i] = hp4[i];                            \
        float ar[2] = {0.f,0.f}, az[2] = {0.f,0.f}, an[2] = {0.f,0.f};         \
        _Pragma("unroll")                                                      \
        for (int i = 0; i < 8; ++i) {                                          \
            const int p = i >> 2;                                              \
            ar[p] = fdot2u(wreg[0][4*i+0], hv[i].x, ar[p]);                    \
            ar[p] = fdot2u(wreg[0][4*i+1], hv[i].y, ar[p]);                    \
            ar[p] = fdot2u(wreg[0][4*i+2], hv[i].z, ar[p]);                    \
            ar[p] = fdot2u(wreg[0][4*i+3], hv[i].w, ar[p]);                    \
            az[p] = fdot2u(wreg[1][4*i+0], hv[i].x, az[p]);                    \
            az[p] = fdot2u(wreg[1][4*i+1], hv[i].y, az[p]);                    \
            az[p] = fdot2u(wreg[1][4*i+2], hv[i].z, az[p]);                    \
            az[p] = fdot2u(wreg[1][4*i+3], hv[i].w, az[p]);                    \
            an[p] = fdot2u(wreg[2][4*i+0], hv[i].x, an[p]);                    \
            an[p] = fdot2u(wreg[2][4*i+1], hv[i].y, an[p]);                    \
            an[p] = fdot2u(wreg[2][4*i+2], hv[i].z, an[p]);                    \
            an[p] = fdot2u(wreg[2][4*i+3], hv[i].w, an[p]);                    \
        }                                                                      \
        const float arr = qadd_xor1(ar[0] + ar[1]);                            \
        const float azz = qadd_xor1(az[0] + az[1]);                            \
        const float ann = qadd_xor1(an[0] + an[1]);                            \
        const float r = fast_sigmoid(giR + arr + bh_r);                        \
        const float z = fast_sigmoid(giZ + azz + bh_z);                        \
        const float n = fast_tanh(giN + r*(ann + bh_n));                       \
        hprev = (1.f - z)*n + z*hprev;                                         \
        if (s == 0) hbuf[WB][u] = (_Float16)hprev;                             \
    }

    #pragma unroll 1
    for (int qi = 0; qi < 128; qi += 4) {
        GRU_BODY(0, 1, 0, (qi+4 < 128 ? qi+4 : 127));
        __syncthreads();
        GRU_BODY(1, 0, 1, (qi+5 < 128 ? qi+5 : 127));
        __syncthreads();
        GRU_BODY(0, 1, 2, (qi+6 < 128 ? qi+6 : 127));
        __syncthreads();
        GRU_BODY(1, 0, 3, (qi+7 < 128 ? qi+7 : 127));
        __syncthreads();
    }
#undef GRU_BODY

    // ---- fused classifier MLP (fp32 h) ----
    if (s == 0) hcls[u] = hprev;
    __syncthreads();
    if (tid < 128) {
        float acc = c1b[tid];
        const float4* wc = (const float4*)(c1w + (size_t)tid*128);
        const float4* v  = (const float4*)hcls;
        #pragma unroll
        for (int d4 = 0; d4 < 32; ++d4) acc += dot4(wc[d4], v[d4]);
        scr[tid] = fmaxf(acc, 0.f);
    }
    __syncthreads();
    if (tid < 128) {
        float acc = c2b[tid];
        const float4* wc = (const float4*)(c2w + (size_t)tid*128);
        const float4* v  = (const float4*)scr;
        #pragma unroll
        for (int d4 = 0; d4 < 32; ++d4) acc += dot4(wc[d4], v[d4]);
        scr[128 + tid] = fmaxf(acc, 0.f);
    }
    __syncthreads();
    if (tid < 2) {
        float acc = c3b[tid];
        const float4* wc = (const float4*)(c3w + (size_t)tid*128);
        const float4* v  = (const float4*)(scr + 128);
        #pragma unroll
        for (int d4 = 0; d4 < 32; ++d4) acc += dot4(wc[d4], v[d4]);
        out[(size_t)b*2 + tid] = acc;
    }
}

// ---------------------------------------------------------------------------
extern "C" void kernel_launch(void* const* d_in, const int* in_sizes, int n_in,
                              void* d_out, int out_size, void* d_ws, size_t ws_size,
                              hipStream_t stream)
{
    const float* input     = (const float*)d_in[0];
    const float* mask      = (const float*)d_in[1];
    const float* timesteps = (const float*)d_in[2];
    const float* pw        = (const float*)d_in[3];
    const float* pb        = (const float*)d_in[4];
    const float* lw        = (const float*)d_in[5];
    const float* lb        = (const float*)d_in[6];
    const float* q_w       = (const float*)d_in[7];
    const float* q_b       = (const float*)d_in[8];
    const float* q_g       = (const float*)d_in[9];
    const float* q_be      = (const float*)d_in[10];
    const float* k_w       = (const float*)d_in[11];
    const float* k_b       = (const float*)d_in[12];
    const float* k_g       = (const float*)d_in[13];
    const float* k_be      = (const float*)d_in[14];
    const float* attn_g    = (const float*)d_in[15];
    const float* attn_b    = (const float*)d_in[16];
    const float* out_w     = (const float*)d_in[17];
    const float* out_b     = (const float*)d_in[18];
    const float* out_g     = (const float*)d_in[19];
    const float* out_be    = (const float*)d_in[20];
    const float* gru_wih   = (const float*)d_in[21];
    const float* gru_whh   = (const float*)d_in[22];
    const float* gru_bih   = (const float*)d_in[23];
    const float* gru_bhh   = (const float*)d_in[24];
    const float* c1_w      = (const float*)d_in[25];
    const float* c1_b      = (const float*)d_in[26];
    const float* c2_w      = (const float*)d_in[27];
    const float* c2_b      = (const float*)d_in[28];
    const float* c3_w      = (const float*)d_in[29];
    const float* c3_b      = (const float*)d_in[30];

    float* ws   = (float*)d_ws;
    float*  qs   = ws;                    // 128*128             = 16384
    float*  kT   = qs   + 16384;          // 8*128*512           = 524288
    float*  outm = kT   + 524288;         // 8*128*128           = 131072 (unused)
    float*  gi   = outm + 131072;         // 128*8*384           = 393216
    float2* xm   = (float2*)(gi + 393216);// 8*512*32 float2     = 262144 floats

    k_embed_proj<<<328, 128, 0, stream>>>(input, mask, timesteps,
                                          pw, pb, lw, lb,
                                          q_w, q_b, q_g, q_be,
                                          k_w, k_b, k_g, k_be, qs, kT, xm);
    k_attn<<<256, 256, 0, stream>>>(xm, qs, kT,
                                    attn_g, attn_b, out_w, out_b,
                                    out_g, out_be, gru_wih, gru_bih, gi);
    k_gru_cls<<<8, 256, 0, stream>>>(gi, gru_whh, gru_bhh,
                                     c1_w, c1_b, c2_w, c2_b, c3_w, c3_b,
                                     (float*)d_out);
}

// Round 7
// 220.009 us; speedup vs baseline: 1.0483x; 1.0483x over previous
//
#include <hip/hip_runtime.h>
#include <math.h>

#define LN_EPS 1e-5f

typedef _Float16 h2v __attribute__((ext_vector_type(2)));

__device__ __forceinline__ float dot4(float4 a, float4 b) {
    return a.x*b.x + a.y*b.y + a.z*b.z + a.w*b.w;
}
__device__ __forceinline__ void fma4(float4& a, float s, float4 v) {
    a.x += s*v.x; a.y += s*v.y; a.z += s*v.z; a.w += s*v.w;
}
__device__ __forceinline__ float fast_rcp(float x) {
    return __builtin_amdgcn_rcpf(x);       // v_rcp_f32: 1 instr vs ~10-op IEEE div
}
__device__ __forceinline__ float fast_sigmoid(float x) {
    return fast_rcp(1.f + __expf(-x));     // +-inf safe
}
__device__ __forceinline__ float fast_tanh(float x) {
    return 1.f - 2.f*fast_rcp(__expf(2.f*x) + 1.f);   // +-inf safe
}
__device__ __forceinline__ float fdot2u(unsigned int a, unsigned int b, float c) {
#if __has_builtin(__builtin_amdgcn_fdot2)
    return __builtin_amdgcn_fdot2(__builtin_bit_cast(h2v, a),
                                  __builtin_bit_cast(h2v, b), c, false);
#else
    const h2v av = __builtin_bit_cast(h2v, a);
    const h2v bv = __builtin_bit_cast(h2v, b);
    return c + (float)av[0]*(float)bv[0] + (float)av[1]*(float)bv[1];
#endif
}
__device__ __forceinline__ float wsum64(float v) {
    #pragma unroll
    for (int off = 32; off > 0; off >>= 1) v += __shfl_xor(v, off);
    return v;
}
// pair (2-lane) butterfly add via DPP quad_perm — VALU-speed, no LDS pipe.
__device__ __forceinline__ float qadd_xor1(float v) {
    const int x = __builtin_amdgcn_mov_dpp(__builtin_bit_cast(int, v),
                                           0xB1 /*perm(1,0,3,2)*/, 0xF, 0xF, true);
    return v + __builtin_bit_cast(float, x);
}

// ---------------------------------------------------------------------------
// Kernel 1: blocks 0..63 = xm transpose; 64..95 = query rows (4/blk);
// 96..1119 = key rows (4/blk) -> kT[b][d][t].
// R14 = exact restoration of the best-measured R3 configuration (220.3us).
// R6's 16-row reblocking regressed (~5.1t vs 4.4t serial-latency trade).
// ---------------------------------------------------------------------------
__global__ void k_embed_proj(
    const float* __restrict__ input, const float* __restrict__ mask,
    const float* __restrict__ timesteps,
    const float* __restrict__ pw, const float* __restrict__ pb,
    const float* __restrict__ lw, const float* __restrict__ lb,
    const float* __restrict__ q_w, const float* __restrict__ q_b,
    const float* __restrict__ q_g, const float* __restrict__ q_be,
    const float* __restrict__ k_w, const float* __restrict__ k_b,
    const float* __restrict__ k_g, const float* __restrict__ k_be,
    float* __restrict__ qs, float* __restrict__ kT, float2* __restrict__ xm)
{
    const int blk = blockIdx.x;
    const int tid = threadIdx.x;          // 0..127

    __shared__ __align__(16) float e[4][128];
    __shared__ __align__(16) float proj[4][128];
    __shared__ __align__(16) float2 tile[32][65];
    __shared__ __align__(16) float4 red2[2];
    __shared__ __align__(16) float4 red2b[2];

    if (blk < 64) {
        // ---- xm transpose: 8 blocks per b, 64 t each ----
        const int b  = blk >> 3;
        const int t0 = (blk & 7) * 64;
        const int cg = tid >> 6;          // 0..1
        const int tt = tid & 63;
        #pragma unroll
        for (int c16 = 0; c16 < 16; ++c16) {
            const int c = c16*2 + cg;
            const float m = mask [(size_t)(b*32 + c)*512 + t0 + tt];
            const float x = input[(size_t)(b*32 + c)*512 + t0 + tt];
            const float mm = 1.0f - m;
            tile[c][tt] = make_float2(x*mm, mm);
        }
        __syncthreads();
        const int c2 = tid & 31;
        const int tg = tid >> 5;          // 0..3
        #pragma unroll
        for (int k = 0; k < 16; ++k) {
            const int t = tg*16 + k;
            xm[((size_t)b*512 + t0 + t)*32 + c2] = tile[c2][t];
        }
        return;
    }

    const bool isq = blk < 96;
    float tv[4];
    int kidx0 = 0;
    if (isq) {
        const int q0 = (blk - 64) * 4;
        #pragma unroll
        for (int r = 0; r < 4; ++r) tv[r] = (float)(q0 + r) * (1.0f/127.0f);
    } else {
        kidx0 = (blk - 96) * 4;
        #pragma unroll
        for (int r = 0; r < 4; ++r) tv[r] = timesteps[kidx0 + r];
    }

    float pwj = 0.f, pbj = 0.f;
    if (tid > 0) { pwj = pw[tid-1]; pbj = pb[tid-1]; }
    const float lw0 = lw[0], lb0 = lb[0];
    #pragma unroll
    for (int r = 0; r < 4; ++r)
        e[r][tid] = (tid == 0) ? (tv[r]*lw0 + lb0) : __sinf(tv[r]*pwj + pbj);
    __syncthreads();

    const float* W  = isq ? q_w  : k_w;
    const float* Bv = isq ? q_b  : k_b;
    const float* G  = isq ? q_g  : k_g;
    const float* Be = isq ? q_be : k_be;

    {
        const int jj = tid >> 2, dc = tid & 3;
        const float4* e0 = (const float4*)(&e[0][0]);
        const float4* e1 = (const float4*)(&e[1][0]);
        const float4* e2 = (const float4*)(&e[2][0]);
        const float4* e3 = (const float4*)(&e[3][0]);
        #pragma unroll
        for (int jb = 0; jb < 4; ++jb) {
            const int j = jb*32 + jj;
            const float4* wrow = (const float4*)(W + (size_t)j*128);
            float a0=0.f, a1=0.f, a2=0.f, a3=0.f;
            #pragma unroll
            for (int k = 0; k < 8; ++k) {
                const int idx = dc + 4*k;
                const float4 w4 = wrow[idx];
                a0 += dot4(w4, e0[idx]);
                a1 += dot4(w4, e1[idx]);
                a2 += dot4(w4, e2[idx]);
                a3 += dot4(w4, e3[idx]);
            }
            a0 += __shfl_xor(a0, 1, 4); a0 += __shfl_xor(a0, 2, 4);
            a1 += __shfl_xor(a1, 1, 4); a1 += __shfl_xor(a1, 2, 4);
            a2 += __shfl_xor(a2, 1, 4); a2 += __shfl_xor(a2, 2, 4);
            a3 += __shfl_xor(a3, 1, 4); a3 += __shfl_xor(a3, 2, 4);
            if (dc == 0) {
                const float bj = Bv[j];
                proj[0][j] = a0 + bj; proj[1][j] = a1 + bj;
                proj[2][j] = a2 + bj; proj[3][j] = a3 + bj;
            }
        }
    }
    __syncthreads();

    float acc[4];
    #pragma unroll
    for (int r = 0; r < 4; ++r) acc[r] = proj[r][tid];

    // ---- LN mean via per-wave shfl reduce + 2-slot combine ----
    {
        float4 m4;
        m4.x = wsum64(acc[0]); m4.y = wsum64(acc[1]);
        m4.z = wsum64(acc[2]); m4.w = wsum64(acc[3]);
        if ((tid & 63) == 0) red2[tid >> 6] = m4;
    }
    __syncthreads();
    float4 mean;
    mean.x = (red2[0].x + red2[1].x) * (1.0f/128.0f);
    mean.y = (red2[0].y + red2[1].y) * (1.0f/128.0f);
    mean.z = (red2[0].z + red2[1].z) * (1.0f/128.0f);
    mean.w = (red2[0].w + red2[1].w) * (1.0f/128.0f);

    const float d0 = acc[0]-mean.x, d1 = acc[1]-mean.y,
                d2 = acc[2]-mean.z, d3 = acc[3]-mean.w;
    {
        float4 s4;
        s4.x = wsum64(d0*d0); s4.y = wsum64(d1*d1);
        s4.z = wsum64(d2*d2); s4.w = wsum64(d3*d3);
        if ((tid & 63) == 0) red2b[tid >> 6] = s4;
    }
    __syncthreads();
    float4 var;
    var.x = (red2b[0].x + red2b[1].x) * (1.0f/128.0f);
    var.y = (red2b[0].y + red2b[1].y) * (1.0f/128.0f);
    var.z = (red2b[0].z + red2b[1].z) * (1.0f/128.0f);
    var.w = (red2b[0].w + red2b[1].w) * (1.0f/128.0f);

    const float gg = G[tid], bb = Be[tid];
    const float o0 = d0*rsqrtf(var.x+LN_EPS)*gg + bb;
    const float o1 = d1*rsqrtf(var.y+LN_EPS)*gg + bb;
    const float o2 = d2*rsqrtf(var.z+LN_EPS)*gg + bb;
    const float o3 = d3*rsqrtf(var.w+LN_EPS)*gg + bb;

    if (isq) {
        const float sc = 0.08838834764831845f;   // 1/sqrt(128)
        const int q0 = (blk - 64)*4;
        qs[(size_t)(q0+0)*128 + tid] = o0*sc;
        qs[(size_t)(q0+1)*128 + tid] = o1*sc;
        qs[(size_t)(q0+2)*128 + tid] = o2*sc;
        qs[(size_t)(q0+3)*128 + tid] = o3*sc;
    } else {
        const int b = kidx0 >> 9;
        const int t = kidx0 & 511;
        *(float4*)(kT + ((size_t)(b*128 + tid))*512 + t) =
            make_float4(o0, o1, o2, o3);
    }
}

// ---------------------------------------------------------------------------
// Kernel 2: attention. 256 blocks = (b, 4 qi), 256 threads.
// ---------------------------------------------------------------------------
__global__ void __launch_bounds__(256) k_attn(
    const float2* __restrict__ xm,
    const float* __restrict__ qs, const float* __restrict__ kT,
    const float* __restrict__ attn_g, const float* __restrict__ attn_b,
    const float* __restrict__ out_w, const float* __restrict__ out_b,
    const float* __restrict__ out_g, const float* __restrict__ out_be,
    float* __restrict__ outm)
{
    const int b     = blockIdx.x >> 5;
    const int qbase = (blockIdx.x & 31) * 4;
    const int tid   = threadIdx.x;          // 0..255

    __shared__ __align__(16) float et[4][512];
    __shared__ __align__(16) float qsh[4][128];
    __shared__ __align__(16) float wsh[128*66];
    __shared__ __align__(16) float sA[4][8][32];
    __shared__ __align__(16) float aA[4][8][32];
    __shared__ __align__(16) float x2s[4][64];
    __shared__ float redC[4];

    for (int idx = tid; idx < 512; idx += 256)
        qsh[idx >> 7][idx & 127] = qs[(size_t)(qbase + (idx >> 7))*128 + (idx & 127)];
    __syncthreads();

    // ---- scores: group handles 2 qi; 4-deep register pipeline on kT ----
    {
        const int grp = tid >> 7;
        const int tl  = tid & 127;
        const int q0  = grp*2;
        const float4* kp  = (const float4*)kT + (size_t)b*128*128 + tl;
        const float4* qa4 = (const float4*)qsh[q0];
        const float4* qb4 = (const float4*)qsh[q0+1];
        float4 a0 = make_float4(0,0,0,0), a1 = make_float4(0,0,0,0);
        float4 c0 = kp[0], c1 = kp[128], c2 = kp[256], c3 = kp[384];
        for (int c = 0; c < 32; ++c) {
            float4 n0, n1, n2, n3;
            if (c < 31) {
                const float4* kn = kp + (size_t)(4*c+4)*128;
                n0 = kn[0]; n1 = kn[128]; n2 = kn[256]; n3 = kn[384];
            }
            const float4 qa = qa4[c], qb = qb4[c];
            fma4(a0, qa.x, c0); fma4(a1, qb.x, c0);
            fma4(a0, qa.y, c1); fma4(a1, qb.y, c1);
            fma4(a0, qa.z, c2); fma4(a1, qb.z, c2);
            fma4(a0, qa.w, c3); fma4(a1, qb.w, c3);
            c0 = n0; c1 = n1; c2 = n2; c3 = n3;
        }
        a0.x = __expf(a0.x); a0.y = __expf(a0.y); a0.z = __expf(a0.z); a0.w = __expf(a0.w);
        a1.x = __expf(a1.x); a1.y = __expf(a1.y); a1.z = __expf(a1.z); a1.w = __expf(a1.w);
        ((float4*)et[q0])[tl]   = a0;
        ((float4*)et[q0+1])[tl] = a1;
    }
    // stage out_w while et/xm phases run (needed only in the last phase)
    for (int idx = tid; idx < 8192; idx += 256)
        wsh[(idx >> 6)*66 + (idx & 63)] = out_w[idx];
    __syncthreads();

    {
        const int c   = tid & 31;
        const int seg = tid >> 5;
        const float2* xp = xm + ((size_t)b*512 + seg*64)*32 + c;
        float s0=0,s1=0,s2=0,s3=0, a0=0,a1=0,a2=0,a3=0;
        #pragma unroll 4
        for (int i = 0; i < 64; ++i) {
            const float2 v = xp[(size_t)i*32];
            const int t = seg*64 + i;
            const float w0 = et[0][t]*v.y, w1 = et[1][t]*v.y;
            const float w2 = et[2][t]*v.y, w3 = et[3][t]*v.y;
            s0 += w0; s1 += w1; s2 += w2; s3 += w3;
            a0 += w0*v.x; a1 += w1*v.x; a2 += w2*v.x; a3 += w3*v.x;
        }
        sA[0][seg][c]=s0; sA[1][seg][c]=s1; sA[2][seg][c]=s2; sA[3][seg][c]=s3;
        aA[0][seg][c]=a0; aA[1][seg][c]=a1; aA[2][seg][c]=a2; aA[3][seg][c]=a3;
    }
    __syncthreads();

    {
        const int ql = tid >> 6;
        const int c2 = tid & 63;
        const int cc = c2 & 31;
        float ss = 0.f;
        #pragma unroll
        for (int g = 0; g < 8; ++g) ss += sA[ql][g][cc];
        float attv;
        if (c2 < 32) {
            float aa = 0.f;
            #pragma unroll
            for (int g = 0; g < 8; ++g) aa += aA[ql][g][cc];
            attv = (ss > 0.f) ? aa/ss : 0.f;
        } else {
            attv = (ss > 0.f) ? 1.0f : 0.0f;
        }
        const float mean = wsum64(attv) * (1.0f/64.0f);
        const float dv = attv - mean;
        const float var = wsum64(dv*dv) * (1.0f/64.0f);
        x2s[ql][c2] = dv*rsqrtf(var+LN_EPS)*attn_g[c2] + attn_b[c2];
    }
    __syncthreads();

    {
        const int jhalf = tid >> 7;
        const int j     = tid & 127;
        const int wave  = tid >> 6;
        for (int lq2 = 0; lq2 < 2; ++lq2) {
            const int ql = jhalf*2 + lq2;
            float acc = out_b[j];
            const float4* wrow = (const float4*)(wsh + j*66);
            const float4* xr   = (const float4*)x2s[ql];
            #pragma unroll
            for (int k = 0; k < 16; ++k) acc += dot4(wrow[k], xr[k]);

            float v = wsum64(acc);
            if ((tid & 63) == 0) redC[wave] = v;
            __syncthreads();
            const float mean = (redC[jhalf*2] + redC[jhalf*2+1]) * (1.0f/128.0f);
            __syncthreads();
            const float d = acc - mean;
            v = wsum64(d*d);
            if ((tid & 63) == 0) redC[wave] = v;
            __syncthreads();
            const float var = (redC[jhalf*2] + redC[jhalf*2+1]) * (1.0f/128.0f);
            outm[((size_t)b*128 + qbase + ql)*128 + j] =
                d*rsqrtf(var+LN_EPS)*out_g[j] + out_be[j];
            __syncthreads();
        }
    }
}

// ---------------------------------------------------------------------------
// Kernel 3: gi[qi][b][g] = outm[b,qi,:]·wih[g,:] + bih[g]
// ---------------------------------------------------------------------------
__global__ void k_gi(const float* __restrict__ outm,
                     const float* __restrict__ wih, const float* __restrict__ bih,
                     float* __restrict__ gi)
{
    const int qi  = blockIdx.x;
    const int tid = threadIdx.x;   // 0..383
    __shared__ __align__(16) float rows[8][128];
    for (int idx = tid; idx < 1024; idx += 384) {
        const int b = idx >> 7, d = idx & 127;
        rows[b][d] = outm[(size_t)(b*128+qi)*128 + d];
    }
    __syncthreads();

    const int g0 = tid >> 2, dc = tid & 3;
    #pragma unroll
    for (int gb = 0; gb < 4; ++gb) {
        const int g = gb*96 + g0;
        const float4* wrow = (const float4*)(wih + (size_t)g*128);
        float acc[8] = {0,0,0,0,0,0,0,0};
        #pragma unroll
        for (int k = 0; k < 8; ++k) {
            const int idx = dc + 4*k;
            const float4 w4 = wrow[idx];
            #pragma unroll
            for (int b = 0; b < 8; ++b)
                acc[b] += dot4(w4, ((const float4*)rows[b])[idx]);
        }
        #pragma unroll
        for (int b = 0; b < 8; ++b) {
            acc[b] += __shfl_xor(acc[b], 1, 4);
            acc[b] += __shfl_xor(acc[b], 2, 4);
        }
        if (dc == 0) {
            const float bi = bih[g];
            #pragma unroll
            for (int b = 0; b < 8; ++b)
                gi[((size_t)qi*8 + b)*384 + g] = acc[b] + bi;
        }
    }
}

// ---------------------------------------------------------------------------
// Kernel 4: GRU + fused classifier. 8 blocks x 256 threads (4 waves, 1/SIMD).
// Best-measured configuration (62.0-63.0us across R3/R6). Structural floor:
// 6 variants bracket it (8w: 85/73/70; 4w: 63/65/62; 2w: 87). The ~660cyc/
// step non-issue time is cross-wave h-exchange latency + barrier arrival that
// 1 wave/SIMD cannot hide; fewer waves violate the 256-VGPR/wave cap (192
// weight regs + working set), more waves convoy on the barrier.
// ---------------------------------------------------------------------------
__global__ void __launch_bounds__(256) k_gru_cls(
    const float* __restrict__ gi,
    const float* __restrict__ whh, const float* __restrict__ bhh,
    const float* __restrict__ c1w, const float* __restrict__ c1b,
    const float* __restrict__ c2w, const float* __restrict__ c2b,
    const float* __restrict__ c3w, const float* __restrict__ c3b,
    float* __restrict__ out)
{
    const int b   = blockIdx.x;
    const int tid = threadIdx.x;                 // 0..255
    const int u   = tid >> 1;                    // unit 0..127
    const int s   = tid & 1;                     // 64-col k-slice 0..1

    __shared__ __align__(16) _Float16 hbuf[2][128];      // h as fp16, dbuf
    __shared__ __align__(16) float hcls[128];
    __shared__ __align__(16) float scr[256];

    // ---- whh rows {u, u+128, u+256}, cols [64s,64s+64) -> fp16 pairs in regs
    unsigned int wreg[3][32];
    #pragma unroll
    for (int g = 0; g < 3; ++g) {
        const float4* wrow = (const float4*)(whh + (size_t)(g*128 + u)*128 + 64*s);
        #pragma unroll
        for (int i = 0; i < 16; ++i) {
            const float4 v = wrow[i];
            h2v p0; p0[0] = (_Float16)v.x; p0[1] = (_Float16)v.y;
            h2v p1; p1[0] = (_Float16)v.z; p1[1] = (_Float16)v.w;
            wreg[g][2*i]   = __builtin_bit_cast(unsigned int, p0);
            wreg[g][2*i+1] = __builtin_bit_cast(unsigned int, p1);
        }
    }
    const float bh_r = bhh[u], bh_z = bhh[u+128], bh_n = bhh[u+256];

    const float* gpR = gi + (size_t)b*384 + u;
    const float* gpZ = gpR + 128;
    const float* gpN = gpR + 256;

    // 4-deep gi pipeline: slot j holds step qi+j (compile-time indices only).
    float gR[4], gZ[4], gN[4];
    #pragma unroll
    for (int j = 0; j < 4; ++j) {
        gR[j] = gpR[(size_t)j*3072];
        gZ[j] = gpZ[(size_t)j*3072];
        gN[j] = gpN[(size_t)j*3072];
    }

    if (tid < 128) { hbuf[0][tid] = (_Float16)0.f; hbuf[1][tid] = (_Float16)0.f; }
    float hprev = 0.f;
    __syncthreads();

    // Body J (step qi+J): read h from hbuf[RB], write new h to hbuf[WB].
    // Consumes gi slot J, then reloads it for step PF = qi+4+J (clamped).
#define GRU_BODY(RB, WB, J, PF)                                                \
    {                                                                          \
        const float giR = gR[J], giZ = gZ[J], giN = gN[J];                     \
        gR[J] = gpR[(size_t)(PF)*3072];                                        \
        gZ[J] = gpZ[(size_t)(PF)*3072];                                        \
        gN[J] = gpN[(size_t)(PF)*3072];                                        \
        const uint4* hp4 = (const uint4*)&hbuf[RB][0] + s*8;                   \
        uint4 hv[8];                                                           \
        _Pragma("unroll")                                                      \
        for (int i = 0; i < 8; ++i) hv[i] = hp4[i];                            \
        float ar[2] = {0.f,0.f}, az[2] = {0.f,0.f}, an[2] = {0.f,0.f};         \
        _Pragma("unroll")                                                      \
        for (int i = 0; i < 8; ++i) {                                          \
            const int p = i >> 2;                                              \
            ar[p] = fdot2u(wreg[0][4*i+0], hv[i].x, ar[p]);                    \
            ar[p] = fdot2u(wreg[0][4*i+1], hv[i].y, ar[p]);                    \
            ar[p] = fdot2u(wreg[0][4*i+2], hv[i].z, ar[p]);                    \
            ar[p] = fdot2u(wreg[0][4*i+3], hv[i].w, ar[p]);                    \
            az[p] = fdot2u(wreg[1][4*i+0], hv[i].x, az[p]);                    \
            az[p] = fdot2u(wreg[1][4*i+1], hv[i].y, az[p]);                    \
            az[p] = fdot2u(wreg[1][4*i+2], hv[i].z, az[p]);                    \
            az[p] = fdot2u(wreg[1][4*i+3], hv[i].w, az[p]);                    \
            an[p] = fdot2u(wreg[2][4*i+0], hv[i].x, an[p]);                    \
            an[p] = fdot2u(wreg[2][4*i+1], hv[i].y, an[p]);                    \
            an[p] = fdot2u(wreg[2][4*i+2], hv[i].z, an[p]);                    \
            an[p] = fdot2u(wreg[2][4*i+3], hv[i].w, an[p]);                    \
        }                                                                      \
        const float arr = qadd_xor1(ar[0] + ar[1]);                            \
        const float azz = qadd_xor1(az[0] + az[1]);                            \
        const float ann = qadd_xor1(an[0] + an[1]);                            \
        const float r = fast_sigmoid(giR + arr + bh_r);                        \
        const float z = fast_sigmoid(giZ + azz + bh_z);                        \
        const float n = fast_tanh(giN + r*(ann + bh_n));                       \
        hprev = (1.f - z)*n + z*hprev;                                         \
        if (s == 0) hbuf[WB][u] = (_Float16)hprev;                             \
    }

    #pragma unroll 1
    for (int qi = 0; qi < 128; qi += 4) {
        GRU_BODY(0, 1, 0, (qi+4 < 128 ? qi+4 : 127));
        __syncthreads();
        GRU_BODY(1, 0, 1, (qi+5 < 128 ? qi+5 : 127));
        __syncthreads();
        GRU_BODY(0, 1, 2, (qi+6 < 128 ? qi+6 : 127));
        __syncthreads();
        GRU_BODY(1, 0, 3, (qi+7 < 128 ? qi+7 : 127));
        __syncthreads();
    }
#undef GRU_BODY

    // ---- fused classifier MLP (fp32 h) ----
    if (s == 0) hcls[u] = hprev;
    __syncthreads();
    if (tid < 128) {
        float acc = c1b[tid];
        const float4* wc = (const float4*)(c1w + (size_t)tid*128);
        const float4* v  = (const float4*)hcls;
        #pragma unroll
        for (int d4 = 0; d4 < 32; ++d4) acc += dot4(wc[d4], v[d4]);
        scr[tid] = fmaxf(acc, 0.f);
    }
    __syncthreads();
    if (tid < 128) {
        float acc = c2b[tid];
        const float4* wc = (const float4*)(c2w + (size_t)tid*128);
        const float4* v  = (const float4*)scr;
        #pragma unroll
        for (int d4 = 0; d4 < 32; ++d4) acc += dot4(wc[d4], v[d4]);
        scr[128 + tid] = fmaxf(acc, 0.f);
    }
    __syncthreads();
    if (tid < 2) {
        float acc = c3b[tid];
        const float4* wc = (const float4*)(c3w + (size_t)tid*128);
        const float4* v  = (const float4*)(scr + 128);
        #pragma unroll
        for (int d4 = 0; d4 < 32; ++d4) acc += dot4(wc[d4], v[d4]);
        out[(size_t)b*2 + tid] = acc;
    }
}

// ---------------------------------------------------------------------------
extern "C" void kernel_launch(void* const* d_in, const int* in_sizes, int n_in,
                              void* d_out, int out_size, void* d_ws, size_t ws_size,
                              hipStream_t stream)
{
    const float* input     = (const float*)d_in[0];
    const float* mask      = (const float*)d_in[1];
    const float* timesteps = (const float*)d_in[2];
    const float* pw        = (const float*)d_in[3];
    const float* pb        = (const float*)d_in[4];
    const float* lw        = (const float*)d_in[5];
    const float* lb        = (const float*)d_in[6];
    const float* q_w       = (const float*)d_in[7];
    const float* q_b       = (const float*)d_in[8];
    const float* q_g       = (const float*)d_in[9];
    const float* q_be      = (const float*)d_in[10];
    const float* k_w       = (const float*)d_in[11];
    const float* k_b       = (const float*)d_in[12];
    const float* k_g       = (const float*)d_in[13];
    const float* k_be      = (const float*)d_in[14];
    const float* attn_g    = (const float*)d_in[15];
    const float* attn_b    = (const float*)d_in[16];
    const float* out_w     = (const float*)d_in[17];
    const float* out_b     = (const float*)d_in[18];
    const float* out_g     = (const float*)d_in[19];
    const float* out_be    = (const float*)d_in[20];
    const float* gru_wih   = (const float*)d_in[21];
    const float* gru_whh   = (const float*)d_in[22];
    const float* gru_bih   = (const float*)d_in[23];
    const float* gru_bhh   = (const float*)d_in[24];
    const float* c1_w      = (const float*)d_in[25];
    const float* c1_b      = (const float*)d_in[26];
    const float* c2_w      = (const float*)d_in[27];
    const float* c2_b      = (const float*)d_in[28];
    const float* c3_w      = (const float*)d_in[29];
    const float* c3_b      = (const float*)d_in[30];

    float* ws   = (float*)d_ws;
    float*  qs   = ws;                    // 128*128             = 16384
    float*  kT   = qs   + 16384;          // 8*128*512           = 524288
    float*  outm = kT   + 524288;         // 8*128*128           = 131072
    float*  gi   = outm + 131072;         // 128*8*384           = 393216
    float2* xm   = (float2*)(gi + 393216);// 8*512*32 float2     = 262144 floats

    k_embed_proj<<<1120, 128, 0, stream>>>(input, mask, timesteps,
                                           pw, pb, lw, lb,
                                           q_w, q_b, q_g, q_be,
                                           k_w, k_b, k_g, k_be, qs, kT, xm);
    k_attn<<<256, 256, 0, stream>>>(xm, qs, kT,
                                    attn_g, attn_b, out_w, out_b,
                                    out_g, out_be, outm);
    k_gi<<<128, 384, 0, stream>>>(outm, gru_wih, gru_bih, gi);
    k_gru_cls<<<8, 256, 0, stream>>>(gi, gru_whh, gru_bhh,
                                     c1_w, c1_b, c2_w, c2_b, c3_w, c3_b,
                                     (float*)d_out);
}